// Round 20
// baseline (179.072 us; speedup 1.0000x reference)
//
#include <hip/hip_runtime.h>

#define NN 4194304
#define NB 16384
#define GRIDP 1024  // 4 blocks/CU x 256 CU: all co-resident at (256,4)

typedef _Float16 half4 __attribute__((ext_vector_type(4)));
typedef float floatx4 __attribute__((ext_vector_type(4)));
typedef unsigned int uint;

__device__ __forceinline__ uint pk_u32(float lo, float hi) {
  return __builtin_bit_cast(uint, __builtin_amdgcn_cvt_pkrtz(lo, hi));
}

__device__ __forceinline__ half4 relu_cvt(floatx4 d) {
  uint2 u;
  u.x = pk_u32(d[0], d[1]);
  u.y = pk_u32(d[2], d[3]);
  half4 h = __builtin_bit_cast(half4, u);
  return __builtin_elementwise_max(h, half4{0, 0, 0, 0});
}

// DPP butterfly wave64 sum; total lands in lane 63. 6 VALU adds, no LDS.
template <int CTRL>
__device__ __forceinline__ float dpp_add(float x) {
  int y = __builtin_amdgcn_update_dpp(0, __builtin_bit_cast(int, x), CTRL,
                                      0xf, 0xf, true);
  return x + __builtin_bit_cast(float, y);
}
__device__ __forceinline__ float wave_sum(float x) {
  x = dpp_add<0x111>(x);
  x = dpp_add<0x112>(x);
  x = dpp_add<0x114>(x);
  x = dpp_add<0x118>(x);
  x = dpp_add<0x142>(x);
  x = dpp_add<0x143>(x);
  return x;
}

// Segmented reduce + atomics. Fast path: wave-uniform segment (avg run = 256).
__device__ __forceinline__ void seg_atomic_add2(int b, float vx, float vy,
                                                float* __restrict__ out) {
  const int lane = threadIdx.x & 63;
  int b0 = __builtin_amdgcn_readfirstlane(b);
  if (__ballot(b == b0) == ~0ull) {
    float sx = wave_sum(vx);
    float sy = wave_sum(vy);
    if (lane == 63) {
      atomicAdd(&out[2 * b0], sx);
      atomicAdd(&out[2 * b0 + 1], sy);
    }
    return;
  }
  int bprev = __shfl_up(b, 1);
  bool head = (lane == 0) || (b != bprev);
  unsigned long long hb = __ballot(head);
  unsigned long long mask_le = hb << (63 - lane);
  int run_start = lane - __clzll(mask_le);
  float sx = vx, sy = vy;
#pragma unroll
  for (int off = 1; off < 64; off <<= 1) {
    float ox = __shfl_up(sx, off);
    float oy = __shfl_up(sy, off);
    if (lane - off >= run_start) { sx += ox; sy += oy; }
  }
  int bnext = __shfl_down(b, 1);
  bool tail = (lane == 63) || (b != bnext);
  if (tail) {
    atomicAdd(&out[2 * b], sx);
    atomicAdd(&out[2 * b + 1], sy);
  }
}

// Prepack weights into A-fragments of mfma_f32_16x16x16f16 (W as A: M=out,K=in).
// ALL biases folded via fake constant-1 neurons (see tile comments).
// Blocks 3..66 zero csum (8192 float4) and out (8192 float4); barrier state
// words zeroed by block 1 (p 448-455).
__global__ void prepack_kernel(
    const float* __restrict__ W1, const float* __restrict__ W2,
    const float* __restrict__ W3, const float* __restrict__ W4,
    const float* __restrict__ W5, const float* __restrict__ B1,
    const float* __restrict__ B2, const float* __restrict__ B3,
    const float* __restrict__ B4, const float* __restrict__ B5,
    uint2* __restrict__ Wf, float* __restrict__ csum,
    float* __restrict__ out, uint* __restrict__ bar) {
  if (blockIdx.x >= 3) {
    int z = (blockIdx.x - 3) * 256 + threadIdx.x;  // 0..16383
    float4 zero{0.f, 0.f, 0.f, 0.f};
    if (z < 8192) ((float4*)csum)[z] = zero;
    else ((float4*)out)[z - 8192] = zero;
    return;
  }
  int p = blockIdx.x * 256 + threadIdx.x;
  if (p >= 456) return;
  if (p >= 448) { bar[p - 448] = 0u; return; }  // reset grid-barrier state
  int tile = p >> 6, lane = p & 63, row = lane & 15, kb = (lane >> 4) * 4;
  float v[4];
#pragma unroll
  for (int i = 0; i < 4; ++i) {
    int k = kb + i;
    float x = 0.f;
    switch (tile) {
      case 0:  // W1 (10x3); k=3: B1; row10 = bias-1 neuron
        if (row < 10 && k < 3) x = W1[row * 3 + k];
        if (k == 3) { if (row < 10) x = B1[row]; else if (row == 10) x = 1.f; }
        break;
      case 1:  // W2 rows 0-15; k=10: B2
        if (k < 10) x = W2[row * 10 + k];
        else if (k == 10) x = B2[row];
        break;
      case 2:  // W2 rows 16-19; k=10: B2[16+]; row4 = bias-1
        if (row < 4 && k < 10) x = W2[(16 + row) * 10 + k];
        if (k == 10) { if (row < 4) x = B2[16 + row]; else if (row == 4) x = 1.f; }
        break;
      case 3:  // W3 k0-15
        if (row < 10 && k < 16) x = W3[row * 20 + k];
        break;
      case 4:  // W3 k16-19; local k4: B3; row10 = bias-1
        if (row < 10 && k < 4) x = W3[row * 20 + 16 + k];
        if (k == 4) { if (row < 10) x = B3[row]; else if (row == 10) x = 1.f; }
        break;
      case 5:  // W4; k=10: B4; row5 = bias-1
        if (row < 5 && k < 10) x = W4[row * 10 + k];
        if (k == 10) { if (row < 5) x = B4[row]; else if (row == 5) x = 1.f; }
        break;
      default:  // W5; k=5: B5
        if (row == 0 && k < 5) x = W5[k];
        if (row == 0 && k == 5) x = B5[0];
        break;
    }
    v[i] = x;
  }
  Wf[p] = uint2{pk_u32(v[0], v[1]), pk_u32(v[2], v[3])};
}

__device__ __forceinline__ floatx4 mfma16(half4 a, half4 b, floatx4 c) {
  return __builtin_amdgcn_mfma_f32_16x16x16f16(a, b, c, 0, 0, 0);
}

// Fused: phase A (centroid atomics, batch+pos cached in regs) -> grid barrier
// -> phase C (MLP, reusing cached batch+pos; csum/poi gathered inline).
// Coherence: csum only touched by memory-side atomics since kernel start, so
// post-barrier normal cached loads are safe (no stale L2 copies can exist).
__global__ __launch_bounds__(256, 4) void fused_kernel(
    const float* __restrict__ t, const float2* __restrict__ pos,
    const float* __restrict__ poi_t, const float2* __restrict__ poi_pos,
    const int* __restrict__ batch, const uint2* __restrict__ Wf,
    float* __restrict__ csum, float* __restrict__ out,
    uint* __restrict__ bar) {
  const int tid = threadIdx.x;
  const int lane = tid & 63;
  const int col = lane & 15;
  const int koct = lane >> 4;
  const float2* csum2 = (const float2*)csum;

  // ---- Load this block's 4096 nodes ONCE (16 r-slots per thread) ----
  int base = blockIdx.x * 4096 + tid;
  int bi[16];
  float2 pv[16];
#pragma unroll
  for (int r = 0; r < 16; ++r) {
    bi[r] = batch[base + r * 256];
    pv[r] = pos[base + r * 256];
  }

  // ---- Phase A: centroid segmented atomics ----
#pragma unroll
  for (int r = 0; r < 16; ++r)
    seg_atomic_add2(bi[r], pv[r].x, pv[r].y, csum);

  // ---- Grid barrier (state zeroed by prepack each call) ----
  __syncthreads();
  if (tid == 0) {
    uint prev = __hip_atomic_fetch_add(&bar[0], 1u, __ATOMIC_ACQ_REL,
                                       __HIP_MEMORY_SCOPE_AGENT);
    if (prev == GRIDP - 1) {
      __hip_atomic_store(&bar[1], 1u, __ATOMIC_RELEASE,
                         __HIP_MEMORY_SCOPE_AGENT);
    } else {
      while (__hip_atomic_load(&bar[1], __ATOMIC_ACQUIRE,
                               __HIP_MEMORY_SCOPE_AGENT) == 0u)
        __builtin_amdgcn_s_sleep(2);
    }
  }
  __syncthreads();

  // Weight A-fragments (all biases folded -> no C fragments).
  half4 wa[7];
#pragma unroll
  for (int k = 0; k < 7; ++k)
    wa[k] = __builtin_bit_cast(half4, Wf[k * 64 + lane]);
  floatx4 cz{0.f, 0.f, 0.f, 0.f};

  // ---- Phase C: 8 passes x 2 r -> 8 MFMA chains per layer (R14 body) ----
#pragma unroll
  for (int rp = 0; rp < 8; ++rp) {
    float dpx[2], dpy[2], f1v[2], invr[2];
    int fx[2], fy[2];
#pragma unroll
    for (int u = 0; u < 2; ++u) {
      int r = rp * 2 + u;
      float tv = t[base + r * 256];        // streamed here, not cached
      float2 pp = poi_pos[bi[r]];
      float2 cs = csum2[bi[r]];
      float pt = poi_t[bi[r]];
      float f0 = tv - pt;
      float dcx = cs.x - pp.x;
      float dcy = cs.y - pp.y;
      float invc = rsqrtf(dcx * dcx + dcy * dcy);
      dpx[u] = pv[r].x - pp.x;
      dpy[u] = pv[r].y - pp.y;
      f1v[u] = dpx[u] * dpx[u] + dpy[u] * dpy[u];
      invr[u] = rsqrtf(f1v[u]);
      float f2 = (dpx[u] * dcx + dpy[u] * dcy) * invc * invr[u];
      fx[u] = (int)pk_u32(f0, f1v[u]);
      fy[u] = (int)pk_u32(f2, 1.0f);  // 1.0 feeds the folded-bias column
    }

    half4 b1[8];
#pragma unroll
    for (int u = 0; u < 2; ++u)
#pragma unroll
      for (int g = 0; g < 4; ++g) {
        int src = g * 16 + col;
        uint2 fr;
        fr.x = (uint)__shfl(fx[u], src);
        fr.y = (uint)__shfl(fy[u], src);
        b1[u * 4 + g] = __builtin_bit_cast(half4, fr);
      }

    floatx4 d[8];
    half4 a[8];
#pragma unroll
    for (int c = 0; c < 8; ++c) d[c] = mfma16(wa[0], b1[c], cz);  // L1
#pragma unroll
    for (int c = 0; c < 8; ++c) a[c] = relu_cvt(d[c]);

    floatx4 d2[8];
    half4 a3a[8], a3b[8];
#pragma unroll
    for (int c = 0; c < 8; ++c) d2[c] = mfma16(wa[1], a[c], cz);  // L2 M0-15
#pragma unroll
    for (int c = 0; c < 8; ++c) a3a[c] = relu_cvt(d2[c]);
#pragma unroll
    for (int c = 0; c < 8; ++c) d2[c] = mfma16(wa[2], a[c], cz);  // L2 M16-20
#pragma unroll
    for (int c = 0; c < 8; ++c) a3b[c] = relu_cvt(d2[c]);

#pragma unroll
    for (int c = 0; c < 8; ++c) d[c] = mfma16(wa[3], a3a[c], cz); // L3 k0-15
#pragma unroll
    for (int c = 0; c < 8; ++c) d[c] = mfma16(wa[4], a3b[c], d[c]); // L3 k16+
#pragma unroll
    for (int c = 0; c < 8; ++c) a[c] = relu_cvt(d[c]);

#pragma unroll
    for (int c = 0; c < 8; ++c) d[c] = mfma16(wa[5], a[c], cz);   // L4
#pragma unroll
    for (int c = 0; c < 8; ++c) a[c] = relu_cvt(d[c]);

#pragma unroll
    for (int c = 0; c < 8; ++c) d[c] = mfma16(wa[6], a[c], cz);   // L5

#pragma unroll
    for (int u = 0; u < 2; ++u) {
      float wg0 = __shfl(d[u * 4 + 0][0], col);
      float wg1 = __shfl(d[u * 4 + 1][0], col);
      float wg2 = __shfl(d[u * 4 + 2][0], col);
      float wg3 = __shfl(d[u * 4 + 3][0], col);
      float w = wg0;
      w = (koct == 1) ? wg1 : w;
      w = (koct == 2) ? wg2 : w;
      w = (koct == 3) ? wg3 : w;
      float invn = (f1v[u] > 0.f) ? invr[u] : 0.f;
      seg_atomic_add2(bi[rp * 2 + u], w * dpx[u] * invn, w * dpy[u] * invn,
                      out);
    }
  }
}

extern "C" void kernel_launch(void* const* d_in, const int* in_sizes, int n_in,
                              void* d_out, int out_size, void* d_ws,
                              size_t ws_size, hipStream_t stream) {
  const float* t = (const float*)d_in[0];
  const float2* pos = (const float2*)d_in[1];
  const float* poi_t = (const float*)d_in[2];
  const float2* poi_pos = (const float2*)d_in[3];
  const int* batch = (const int*)d_in[4];
  const float* W1 = (const float*)d_in[5];
  const float* B1 = (const float*)d_in[6];
  const float* W2 = (const float*)d_in[7];
  const float* B2 = (const float*)d_in[8];
  const float* W3 = (const float*)d_in[9];
  const float* B3 = (const float*)d_in[10];
  const float* W4 = (const float*)d_in[11];
  const float* B4 = (const float*)d_in[12];
  const float* W5 = (const float*)d_in[13];
  const float* B5 = (const float*)d_in[14];
  float* out = (float*)d_out;

  float* csum = (float*)d_ws;                  // [NB*2]
  uint2* Wf = (uint2*)(csum + 2 * NB);         // [448]
  uint* bar = (uint*)(Wf + 448);               // [8]

  // prepack: blocks 0-2 pack weights + reset barrier; 3-66 zero csum + out.
  prepack_kernel<<<67, 256, 0, stream>>>(W1, W2, W3, W4, W5, B1, B2, B3, B4,
                                         B5, Wf, csum, out, bar);
  fused_kernel<<<GRIDP, 256, 0, stream>>>(t, pos, poi_t, poi_pos, batch, Wf,
                                          csum, out, bar);
}

// Round 21
// 50.374 us; speedup vs baseline: 3.5548x; 3.5548x over previous
//
#include <hip/hip_runtime.h>

#define NN 4194304
#define NB 16384

typedef _Float16 half4 __attribute__((ext_vector_type(4)));
typedef float floatx4 __attribute__((ext_vector_type(4)));
typedef unsigned int uint;

__device__ __forceinline__ uint pk_u32(float lo, float hi) {
  return __builtin_bit_cast(uint, __builtin_amdgcn_cvt_pkrtz(lo, hi));
}

__device__ __forceinline__ half4 relu_cvt(floatx4 d) {
  uint2 u;
  u.x = pk_u32(d[0], d[1]);
  u.y = pk_u32(d[2], d[3]);
  half4 h = __builtin_bit_cast(half4, u);
  return __builtin_elementwise_max(h, half4{0, 0, 0, 0});
}

// DPP butterfly wave64 sum; total lands in lane 63. 6 VALU adds, no LDS.
template <int CTRL>
__device__ __forceinline__ float dpp_add(float x) {
  int y = __builtin_amdgcn_update_dpp(0, __builtin_bit_cast(int, x), CTRL,
                                      0xf, 0xf, true);
  return x + __builtin_bit_cast(float, y);
}
__device__ __forceinline__ float wave_sum(float x) {
  x = dpp_add<0x111>(x);
  x = dpp_add<0x112>(x);
  x = dpp_add<0x114>(x);
  x = dpp_add<0x118>(x);
  x = dpp_add<0x142>(x);
  x = dpp_add<0x143>(x);
  return x;
}

// Segmented reduce + atomics. Fast path: wave-uniform segment (avg run = 256).
__device__ __forceinline__ void seg_atomic_add2(int b, float vx, float vy,
                                                float* __restrict__ out) {
  const int lane = threadIdx.x & 63;
  int b0 = __builtin_amdgcn_readfirstlane(b);
  if (__ballot(b == b0) == ~0ull) {
    float sx = wave_sum(vx);
    float sy = wave_sum(vy);
    if (lane == 63) {
      atomicAdd(&out[2 * b0], sx);
      atomicAdd(&out[2 * b0 + 1], sy);
    }
    return;
  }
  int bprev = __shfl_up(b, 1);
  bool head = (lane == 0) || (b != bprev);
  unsigned long long hb = __ballot(head);
  unsigned long long mask_le = hb << (63 - lane);
  int run_start = lane - __clzll(mask_le);
  float sx = vx, sy = vy;
#pragma unroll
  for (int off = 1; off < 64; off <<= 1) {
    float ox = __shfl_up(sx, off);
    float oy = __shfl_up(sy, off);
    if (lane - off >= run_start) { sx += ox; sy += oy; }
  }
  int bnext = __shfl_down(b, 1);
  bool tail = (lane == 63) || (b != bnext);
  if (tail) {
    atomicAdd(&out[2 * b], sx);
    atomicAdd(&out[2 * b + 1], sy);
  }
}

// 4 nodes/thread: loads hoisted, stalls amortized. (R12/R14-proven shape.)
__global__ __launch_bounds__(256) void centroid_kernel(
    const float2* __restrict__ pos, const int* __restrict__ batch,
    float* __restrict__ csum) {
  int base = blockIdx.x * 1024 + threadIdx.x;
  int bi[4];
  float2 pv[4];
#pragma unroll
  for (int r = 0; r < 4; ++r) {
    bi[r] = batch[base + r * 256];
    pv[r] = pos[base + r * 256];
  }
#pragma unroll
  for (int r = 0; r < 4; ++r) seg_atomic_add2(bi[r], pv[r].x, pv[r].y, csum);
}

// Prepack weights into A-fragments of mfma_f32_16x16x16f16 (W as A: M=out,K=in).
// ALL biases folded via fake constant-1 neurons (see tile comments).
// Blocks 3..66 zero csum (8192 float4) and out (8192 float4).
__global__ void prepack_kernel(
    const float* __restrict__ W1, const float* __restrict__ W2,
    const float* __restrict__ W3, const float* __restrict__ W4,
    const float* __restrict__ W5, const float* __restrict__ B1,
    const float* __restrict__ B2, const float* __restrict__ B3,
    const float* __restrict__ B4, const float* __restrict__ B5,
    uint2* __restrict__ Wf, float* __restrict__ csum,
    float* __restrict__ out) {
  if (blockIdx.x >= 3) {
    int z = (blockIdx.x - 3) * 256 + threadIdx.x;  // 0..16383
    float4 zero{0.f, 0.f, 0.f, 0.f};
    if (z < 8192) ((float4*)csum)[z] = zero;
    else ((float4*)out)[z - 8192] = zero;
    return;
  }
  int p = blockIdx.x * 256 + threadIdx.x;
  if (p >= 448) return;
  int tile = p >> 6, lane = p & 63, row = lane & 15, kb = (lane >> 4) * 4;
  float v[4];
#pragma unroll
  for (int i = 0; i < 4; ++i) {
    int k = kb + i;
    float x = 0.f;
    switch (tile) {
      case 0:  // W1 (10x3); k=3: B1; row10 = bias-1 neuron
        if (row < 10 && k < 3) x = W1[row * 3 + k];
        if (k == 3) { if (row < 10) x = B1[row]; else if (row == 10) x = 1.f; }
        break;
      case 1:  // W2 rows 0-15; k=10: B2
        if (k < 10) x = W2[row * 10 + k];
        else if (k == 10) x = B2[row];
        break;
      case 2:  // W2 rows 16-19; k=10: B2[16+]; row4 = bias-1
        if (row < 4 && k < 10) x = W2[(16 + row) * 10 + k];
        if (k == 10) { if (row < 4) x = B2[16 + row]; else if (row == 4) x = 1.f; }
        break;
      case 3:  // W3 k0-15
        if (row < 10 && k < 16) x = W3[row * 20 + k];
        break;
      case 4:  // W3 k16-19; local k4: B3; row10 = bias-1
        if (row < 10 && k < 4) x = W3[row * 20 + 16 + k];
        if (k == 4) { if (row < 10) x = B3[row]; else if (row == 10) x = 1.f; }
        break;
      case 5:  // W4; k=10: B4; row5 = bias-1
        if (row < 5 && k < 10) x = W4[row * 10 + k];
        if (k == 10) { if (row < 5) x = B4[row]; else if (row == 5) x = 1.f; }
        break;
      default:  // W5; k=5: B5
        if (row == 0 && k < 5) x = W5[k];
        if (row == 0 && k == 5) x = B5[0];
        break;
    }
    v[i] = x;
  }
  Wf[p] = uint2{pk_u32(v[0], v[1]), pk_u32(v[2], v[3])};
}

__device__ __forceinline__ floatx4 mfma16(half4 a, half4 b, floatx4 c) {
  return __builtin_amdgcn_mfma_f32_16x16x16f16(a, b, c, 0, 0, 0);
}

// Graphvec fused in: per-r we load csum/poi_pos/poi_t and compute the unit
// centroid-diff inline (~10 VALU ops) instead of a separate dispatch + pg buf.
__global__ __launch_bounds__(256, 3) void main_kernel(
    const float* __restrict__ t, const float2* __restrict__ pos,
    const float* __restrict__ poi_t, const float2* __restrict__ poi_pos,
    const int* __restrict__ batch, const float2* __restrict__ csum2,
    const uint2* __restrict__ Wf, float* __restrict__ out) {
  const int tid = threadIdx.x;
  const int lane = tid & 63;
  const int col = lane & 15;
  const int koct = lane >> 4;

  // ---- Phase 0: all streaming loads + gathers for 4 iterations upfront ----
  int base = blockIdx.x * 1024 + tid;
  int bi[4];
  float tvv[4];
  float2 pv[4];
#pragma unroll
  for (int r = 0; r < 4; ++r) {
    bi[r] = batch[base + r * 256];
    tvv[r] = t[base + r * 256];
    pv[r] = pos[base + r * 256];
  }
  float2 ppr[4], csr[4];
  float ptg[4];
#pragma unroll
  for (int r = 0; r < 4; ++r) {
    ppr[r] = poi_pos[bi[r]];
    csr[r] = csum2[bi[r]];
    ptg[r] = poi_t[bi[r]];
  }

  // Weight A-fragments (all biases folded -> no C fragments).
  half4 wa[7];
#pragma unroll
  for (int k = 0; k < 7; ++k)
    wa[k] = __builtin_bit_cast(half4, Wf[k * 64 + lane]);
  floatx4 cz{0.f, 0.f, 0.f, 0.f};

  // ---- Phase 1: 2 passes x 2 iterations -> 8 MFMA chains per layer ----
#pragma unroll
  for (int rp = 0; rp < 2; ++rp) {
    float dpx[2], dpy[2], f1v[2], invr[2];
    int fx[2], fy[2];
#pragma unroll
    for (int u = 0; u < 2; ++u) {
      int r = rp * 2 + u;
      float f0 = tvv[r] - ptg[r];
      // inline graphvec: unit vector of (centroid_sum - poi_pos)
      float dcx = csr[r].x - ppr[r].x;
      float dcy = csr[r].y - ppr[r].y;
      float invc = rsqrtf(dcx * dcx + dcy * dcy);
      dpx[u] = pv[r].x - ppr[r].x;
      dpy[u] = pv[r].y - ppr[r].y;
      f1v[u] = dpx[u] * dpx[u] + dpy[u] * dpy[u];
      invr[u] = rsqrtf(f1v[u]);
      float f2 = (dpx[u] * dcx + dpy[u] * dcy) * invc * invr[u];
      fx[u] = (int)pk_u32(f0, f1v[u]);
      fy[u] = (int)pk_u32(f2, 1.0f);  // 1.0 feeds the folded-bias column
    }

    half4 b1[8];
#pragma unroll
    for (int u = 0; u < 2; ++u)
#pragma unroll
      for (int g = 0; g < 4; ++g) {
        int src = g * 16 + col;
        uint2 fr;
        fr.x = (uint)__shfl(fx[u], src);
        fr.y = (uint)__shfl(fy[u], src);
        b1[u * 4 + g] = __builtin_bit_cast(half4, fr);
      }

    floatx4 d[8];
    half4 a[8];
#pragma unroll
    for (int c = 0; c < 8; ++c) d[c] = mfma16(wa[0], b1[c], cz);  // L1
#pragma unroll
    for (int c = 0; c < 8; ++c) a[c] = relu_cvt(d[c]);

    floatx4 d2[8];
    half4 a3a[8], a3b[8];
#pragma unroll
    for (int c = 0; c < 8; ++c) d2[c] = mfma16(wa[1], a[c], cz);  // L2 M0-15
#pragma unroll
    for (int c = 0; c < 8; ++c) a3a[c] = relu_cvt(d2[c]);
#pragma unroll
    for (int c = 0; c < 8; ++c) d2[c] = mfma16(wa[2], a[c], cz);  // L2 M16-20
#pragma unroll
    for (int c = 0; c < 8; ++c) a3b[c] = relu_cvt(d2[c]);

#pragma unroll
    for (int c = 0; c < 8; ++c) d[c] = mfma16(wa[3], a3a[c], cz); // L3 k0-15
#pragma unroll
    for (int c = 0; c < 8; ++c) d[c] = mfma16(wa[4], a3b[c], d[c]); // L3 k16+
#pragma unroll
    for (int c = 0; c < 8; ++c) a[c] = relu_cvt(d[c]);

#pragma unroll
    for (int c = 0; c < 8; ++c) d[c] = mfma16(wa[5], a[c], cz);   // L4
#pragma unroll
    for (int c = 0; c < 8; ++c) a[c] = relu_cvt(d[c]);

#pragma unroll
    for (int c = 0; c < 8; ++c) d[c] = mfma16(wa[6], a[c], cz);   // L5

#pragma unroll
    for (int u = 0; u < 2; ++u) {
      float wg0 = __shfl(d[u * 4 + 0][0], col);
      float wg1 = __shfl(d[u * 4 + 1][0], col);
      float wg2 = __shfl(d[u * 4 + 2][0], col);
      float wg3 = __shfl(d[u * 4 + 3][0], col);
      float w = wg0;
      w = (koct == 1) ? wg1 : w;
      w = (koct == 2) ? wg2 : w;
      w = (koct == 3) ? wg3 : w;
      float invn = (f1v[u] > 0.f) ? invr[u] : 0.f;
      seg_atomic_add2(bi[rp * 2 + u], w * dpx[u] * invn, w * dpy[u] * invn,
                      out);
    }
  }
}

extern "C" void kernel_launch(void* const* d_in, const int* in_sizes, int n_in,
                              void* d_out, int out_size, void* d_ws,
                              size_t ws_size, hipStream_t stream) {
  const float* t = (const float*)d_in[0];
  const float2* pos = (const float2*)d_in[1];
  const float* poi_t = (const float*)d_in[2];
  const float2* poi_pos = (const float2*)d_in[3];
  const int* batch = (const int*)d_in[4];
  const float* W1 = (const float*)d_in[5];
  const float* B1 = (const float*)d_in[6];
  const float* W2 = (const float*)d_in[7];
  const float* B2 = (const float*)d_in[8];
  const float* W3 = (const float*)d_in[9];
  const float* B3 = (const float*)d_in[10];
  const float* W4 = (const float*)d_in[11];
  const float* B4 = (const float*)d_in[12];
  const float* W5 = (const float*)d_in[13];
  const float* B5 = (const float*)d_in[14];
  float* out = (float*)d_out;

  float* csum = (float*)d_ws;                  // [NB*2]
  uint2* Wf = (uint2*)(csum + 2 * NB);         // [448]

  // prepack blocks 0-2 pack weights; blocks 3-66 zero csum + out.
  prepack_kernel<<<67, 256, 0, stream>>>(W1, W2, W3, W4, W5, B1, B2, B3, B4,
                                         B5, Wf, csum, out);
  centroid_kernel<<<NN / 1024, 256, 0, stream>>>(pos, batch, csum);
  main_kernel<<<NN / 1024, 256, 0, stream>>>(t, pos, poi_t, poi_pos, batch,
                                             (const float2*)csum, Wf, out);
}

// Round 22
// 46.405 us; speedup vs baseline: 3.8589x; 1.0855x over previous
//
#include <hip/hip_runtime.h>

#define NNODES 4194304
#define NGRAPH 16384

typedef _Float16 half4 __attribute__((ext_vector_type(4)));
typedef float floatx4 __attribute__((ext_vector_type(4)));
typedef unsigned int uint;

__device__ __forceinline__ uint pk_u32(float lo, float hi) {
  return __builtin_bit_cast(uint, __builtin_amdgcn_cvt_pkrtz(lo, hi));
}

__device__ __forceinline__ half4 relu_cvt(floatx4 d) {
  uint2 u;
  u.x = pk_u32(d[0], d[1]);
  u.y = pk_u32(d[2], d[3]);
  half4 h = __builtin_bit_cast(half4, u);
  return __builtin_elementwise_max(h, half4{0, 0, 0, 0});
}

// DPP butterfly wave64 sum; total lands in lane 63.
template <int CTRL>
__device__ __forceinline__ float dpp_add(float x) {
  int y = __builtin_amdgcn_update_dpp(0, __builtin_bit_cast(int, x), CTRL,
                                      0xf, 0xf, true);
  return x + __builtin_bit_cast(float, y);
}
__device__ __forceinline__ float wave_sum(float x) {
  x = dpp_add<0x111>(x);
  x = dpp_add<0x112>(x);
  x = dpp_add<0x114>(x);
  x = dpp_add<0x118>(x);
  x = dpp_add<0x142>(x);
  x = dpp_add<0x143>(x);
  return x;
}

// Graph boundary scan: start[g] for g in [0, NGRAPH], each written exactly
// once (batch sorted). Empty graphs get start == start of next non-empty.
__global__ __launch_bounds__(256) void scan_kernel(
    const int* __restrict__ batch, int* __restrict__ start) {
  int i = blockIdx.x * 256 + threadIdx.x;
  int b0 = batch[i];
  if (i == 0) {
    for (int g = 0; g <= b0; ++g) start[g] = 0;
  }
  if (i == NNODES - 1) {
    for (int g = b0 + 1; g <= NGRAPH; ++g) start[g] = NNODES;
  } else {
    int b1 = batch[i + 1];
    for (int g = b0 + 1; g <= b1; ++g) start[g] = i + 1;
  }
}

// Prepack weights into A-fragments of mfma_f32_16x16x16f16 (W as A: M=out,K=in).
// ALL biases folded via fake constant-1 neurons. 7 tiles, 448 uint2.
__global__ void prepack_kernel(
    const float* __restrict__ W1, const float* __restrict__ W2,
    const float* __restrict__ W3, const float* __restrict__ W4,
    const float* __restrict__ W5, const float* __restrict__ B1,
    const float* __restrict__ B2, const float* __restrict__ B3,
    const float* __restrict__ B4, const float* __restrict__ B5,
    uint2* __restrict__ Wf) {
  int p = blockIdx.x * 256 + threadIdx.x;
  if (p >= 448) return;
  int tile = p >> 6, lane = p & 63, row = lane & 15, kb = (lane >> 4) * 4;
  float v[4];
#pragma unroll
  for (int i = 0; i < 4; ++i) {
    int k = kb + i;
    float x = 0.f;
    switch (tile) {
      case 0:  // W1 (10x3); k=3: B1; row10 = bias-1 neuron
        if (row < 10 && k < 3) x = W1[row * 3 + k];
        if (k == 3) { if (row < 10) x = B1[row]; else if (row == 10) x = 1.f; }
        break;
      case 1:  // W2 rows 0-15; k=10: B2
        if (k < 10) x = W2[row * 10 + k];
        else if (k == 10) x = B2[row];
        break;
      case 2:  // W2 rows 16-19; k=10: B2[16+]; row4 = bias-1
        if (row < 4 && k < 10) x = W2[(16 + row) * 10 + k];
        if (k == 10) { if (row < 4) x = B2[16 + row]; else if (row == 4) x = 1.f; }
        break;
      case 3:  // W3 k0-15
        if (row < 10 && k < 16) x = W3[row * 20 + k];
        break;
      case 4:  // W3 k16-19; local k4: B3; row10 = bias-1
        if (row < 10 && k < 4) x = W3[row * 20 + 16 + k];
        if (k == 4) { if (row < 10) x = B3[row]; else if (row == 10) x = 1.f; }
        break;
      case 5:  // W4; k=10: B4; row5 = bias-1
        if (row < 5 && k < 10) x = W4[row * 10 + k];
        if (k == 10) { if (row < 5) x = B4[row]; else if (row == 5) x = 1.f; }
        break;
      default:  // W5; k=5: B5
        if (row == 0 && k < 5) x = W5[k];
        if (row == 0 && k == 5) x = B5[0];
        break;
    }
    v[i] = x;
  }
  Wf[p] = uint2{pk_u32(v[0], v[1]), pk_u32(v[2], v[3])};
}

__device__ __forceinline__ floatx4 mfma16(half4 a, half4 b, floatx4 c) {
  return __builtin_amdgcn_mfma_f32_16x16x16f16(a, b, c, 0, 0, 0);
}

// One WAVE per graph: centroid (DPP reduce) -> MLP (4-chain MFMA per 64-node
// iteration) -> single non-atomic out write. No atomics, no zero-init, no
// barrier (graph g only depends on its own contiguous node range).
__global__ __launch_bounds__(256, 4) void fused_kernel(
    const float* __restrict__ t, const float2* __restrict__ pos,
    const float* __restrict__ poi_t, const float2* __restrict__ poi_pos,
    const int* __restrict__ start, const uint2* __restrict__ Wf,
    float* __restrict__ out) {
  const int tid = threadIdx.x;
  const int lane = tid & 63;
  const int wid = tid >> 6;
  const int col = lane & 15;
  const int koct = lane >> 4;
  const int g = blockIdx.x * 4 + wid;

  int s = start[g], e = start[g + 1];
  float2 pp = poi_pos[g];
  float pt = poi_t[g];
  int niter = (e - s + 63) >> 6;

  // ---- Centroid over this graph's nodes (in-wave reduce, no atomics) ----
  float cx = 0.f, cy = 0.f;
  for (int it = 0; it < niter; ++it) {
    int idx = s + it * 64 + lane;
    bool valid = idx < e;
    int idxc = min(idx, NNODES - 1);
    float2 p = pos[idxc];
    if (valid) { cx += p.x; cy += p.y; }
  }
  cx = wave_sum(cx);
  cy = wave_sum(cy);
  cx = __shfl(cx, 63);
  cy = __shfl(cy, 63);
  float dcx = cx - pp.x, dcy = cy - pp.y;
  float invc = rsqrtf(dcx * dcx + dcy * dcy);
  float ucx = dcx * invc, ucy = dcy * invc;

  // Weight A-fragments (biases folded -> C operand is zero).
  half4 wa[7];
#pragma unroll
  for (int k = 0; k < 7; ++k)
    wa[k] = __builtin_bit_cast(half4, Wf[k * 64 + lane]);
  floatx4 cz{0.f, 0.f, 0.f, 0.f};

  // ---- MLP + weighted-unit accumulation ----
  float ox = 0.f, oy = 0.f;
  for (int it = 0; it < niter; ++it) {
    int idx = s + it * 64 + lane;
    bool valid = idx < e;
    int idxc = min(idx, NNODES - 1);
    float tv = t[idxc];
    float2 p = pos[idxc];
    float f0 = tv - pt;
    float dpx = p.x - pp.x, dpy = p.y - pp.y;
    float f1 = dpx * dpx + dpy * dpy;
    float invr = rsqrtf(f1);
    float f2 = (dpx * ucx + dpy * ucy) * invr;
    int fx = (int)pk_u32(f0, f1);
    int fy = (int)pk_u32(f2, 1.0f);  // 1.0 feeds the folded-bias column

    // Gather B1 fragments: group g2 covers nodes (base + g2*16 + col),
    // whose features live in lane g2*16+col. (OOB lanes' NaNs stay in
    // their own output column -> masked at the end.)
    half4 b1[4];
#pragma unroll
    for (int g2 = 0; g2 < 4; ++g2) {
      int src = g2 * 16 + col;
      uint2 fr;
      fr.x = (uint)__shfl(fx, src);
      fr.y = (uint)__shfl(fy, src);
      b1[g2] = __builtin_bit_cast(half4, fr);
    }

    floatx4 d[4];
    half4 a[4];
#pragma unroll
    for (int c = 0; c < 4; ++c) d[c] = mfma16(wa[0], b1[c], cz);   // L1
#pragma unroll
    for (int c = 0; c < 4; ++c) a[c] = relu_cvt(d[c]);

    floatx4 d2[4];
    half4 a3a[4], a3b[4];
#pragma unroll
    for (int c = 0; c < 4; ++c) d2[c] = mfma16(wa[1], a[c], cz);   // L2a
#pragma unroll
    for (int c = 0; c < 4; ++c) a3a[c] = relu_cvt(d2[c]);
#pragma unroll
    for (int c = 0; c < 4; ++c) d2[c] = mfma16(wa[2], a[c], cz);   // L2b
#pragma unroll
    for (int c = 0; c < 4; ++c) a3b[c] = relu_cvt(d2[c]);

#pragma unroll
    for (int c = 0; c < 4; ++c) d[c] = mfma16(wa[3], a3a[c], cz);  // L3a
#pragma unroll
    for (int c = 0; c < 4; ++c) d[c] = mfma16(wa[4], a3b[c], d[c]); // L3b
#pragma unroll
    for (int c = 0; c < 4; ++c) a[c] = relu_cvt(d[c]);

#pragma unroll
    for (int c = 0; c < 4; ++c) d[c] = mfma16(wa[5], a[c], cz);    // L4
#pragma unroll
    for (int c = 0; c < 4; ++c) a[c] = relu_cvt(d[c]);

#pragma unroll
    for (int c = 0; c < 4; ++c) d[c] = mfma16(wa[6], a[c], cz);    // L5

    float wg0 = __shfl(d[0][0], col);
    float wg1 = __shfl(d[1][0], col);
    float wg2 = __shfl(d[2][0], col);
    float wg3 = __shfl(d[3][0], col);
    float w = wg0;
    w = (koct == 1) ? wg1 : w;
    w = (koct == 2) ? wg2 : w;
    w = (koct == 3) ? wg3 : w;
    float invn = (f1 > 0.f) ? invr : 0.f;
    if (valid) {
      ox += w * dpx * invn;
      oy += w * dpy * invn;
    }
  }

  ox = wave_sum(ox);
  oy = wave_sum(oy);
  if (lane == 63) ((float2*)out)[g] = float2{ox, oy};
}

extern "C" void kernel_launch(void* const* d_in, const int* in_sizes, int n_in,
                              void* d_out, int out_size, void* d_ws,
                              size_t ws_size, hipStream_t stream) {
  const float* t = (const float*)d_in[0];
  const float2* pos = (const float2*)d_in[1];
  const float* poi_t = (const float*)d_in[2];
  const float2* poi_pos = (const float2*)d_in[3];
  const int* batch = (const int*)d_in[4];
  const float* W1 = (const float*)d_in[5];
  const float* B1 = (const float*)d_in[6];
  const float* W2 = (const float*)d_in[7];
  const float* B2 = (const float*)d_in[8];
  const float* W3 = (const float*)d_in[9];
  const float* B3 = (const float*)d_in[10];
  const float* W4 = (const float*)d_in[11];
  const float* B4 = (const float*)d_in[12];
  const float* W5 = (const float*)d_in[13];
  const float* B5 = (const float*)d_in[14];
  float* out = (float*)d_out;

  int* start = (int*)d_ws;                     // [NGRAPH+1]
  uint2* Wf = (uint2*)(start + NGRAPH + 1);    // [448]

  prepack_kernel<<<2, 256, 0, stream>>>(W1, W2, W3, W4, W5, B1, B2, B3, B4,
                                        B5, Wf);
  scan_kernel<<<NNODES / 256, 256, 0, stream>>>(batch, start);
  fused_kernel<<<NGRAPH / 4, 256, 0, stream>>>(t, pos, poi_t, poi_pos, start,
                                               Wf, out);
}